// Round 7
// baseline (492.957 us; speedup 1.0000x reference)
//
#include <hip/hip_runtime.h>
#include <stdint.h>
#include <math.h>

#define B_  4
#define N_  1024
#define D_  512
#define H_  8
#define HD_ 64

typedef short s16x8 __attribute__((ext_vector_type(8)));
typedef float f32x4 __attribute__((ext_vector_type(4)));

__device__ __forceinline__ unsigned short f2bf(float f) {
    unsigned u = __float_as_uint(f);
    u += 0x7fffu + ((u >> 16) & 1u);      // RNE
    return (unsigned short)(u >> 16);
}
__device__ __forceinline__ float bf2f(unsigned short h) {
    return __uint_as_float(((unsigned)h) << 16);
}

// fast exact-erf gelu: A&S 7.1.26 rational, |erf err| <= 1.5e-7, branch-free
__device__ __forceinline__ float fast_gelu(float x) {
    float ax = fabsf(x) * 0.7071067811865476f;          // |x|/sqrt(2)
    float t  = __builtin_amdgcn_rcpf(fmaf(0.3275911f, ax, 1.0f));
    float e  = __expf(-ax * ax);
    float poly = t * fmaf(t, fmaf(t, fmaf(t, fmaf(t, 1.061405429f, -1.453152027f),
                                          1.421413741f), -0.284496736f), 0.254829592f);
    float erfv = 1.0f - poly * e;                        // erf(|x|/sqrt2)
    float s = copysignf(erfv, x);
    return 0.5f * x * (1.0f + s);
}

// ---------------- split f32 -> (hi, lo) bf16 ----------------
__global__ void k_split(const float* __restrict__ s, unsigned short* __restrict__ h,
                        unsigned short* __restrict__ l, int n) {
    int i = blockIdx.x * 256 + threadIdx.x;
    if (i < n) {
        float x = s[i];
        unsigned short hb = f2bf(x);
        h[i] = hb;
        l[i] = f2bf(x - bf2f(hb));
    }
}

// ---------------- mask layout detection ----------------
__global__ void k_mask_detect(const unsigned char* __restrict__ m, int* __restrict__ flag) {
    __shared__ int s;
    if (threadIdx.x == 0) s = 0;
    __syncthreads();
    int found = 0;
    for (int i = threadIdx.x; i < B_ * N_; i += 256)
        if ((i & 3) && m[i]) found = 1;
    if (found) atomicOr(&s, 1);
    __syncthreads();
    if (threadIdx.x == 0) flag[0] = s;
}

// ---------------- split-bf16 GEMM: C[M,N] = A[M,K] @ B[N,K]^T (+bias) ----------------
__global__ __launch_bounds__(256) void k_gemm3(
    const unsigned short* __restrict__ Ah, const unsigned short* __restrict__ Al,
    const unsigned short* __restrict__ Bwh, const unsigned short* __restrict__ Bwl,
    float* __restrict__ C, const float* __restrict__ bias, int M, int Nn, int K)
{
    constexpr int BM = 64, BN = 128, BK = 64;
    __shared__ unsigned short At[BM * BK];
    __shared__ unsigned short Bt[BN * BK];
    const int tid = threadIdx.x, lane = tid & 63, wid = tid >> 6;
    const int m0 = blockIdx.x * BM, n0 = blockIdx.y * BN;
    const int wm = wid >> 1, wn = wid & 1;   // wave tile: 32 rows x 64 cols
    f32x4 acc[2][4] = {};
    const unsigned short* Aps[3] = {Ah, Ah, Al};
    const unsigned short* Bps[3] = {Bwh, Bwl, Bwh};

    for (int combo = 0; combo < 3; ++combo) {
        const unsigned short* __restrict__ Ap = Aps[combo];
        const unsigned short* __restrict__ Bp = Bps[combo];
        for (int k0 = 0; k0 < K; k0 += BK) {
            s16x8 sa[2], sb[4];
            #pragma unroll
            for (int r = 0; r < 2; ++r) {
                int s = r * 256 + tid, row = s >> 3, c8 = s & 7;
                sa[r] = *(const s16x8*)(Ap + (size_t)(m0 + row) * K + k0 + c8 * 8);
            }
            #pragma unroll
            for (int r = 0; r < 4; ++r) {
                int s = r * 256 + tid, row = s >> 3, c8 = s & 7;
                sb[r] = *(const s16x8*)(Bp + (size_t)(n0 + row) * K + k0 + c8 * 8);
            }
            __syncthreads();  // previous-iter LDS reads done
            #pragma unroll
            for (int r = 0; r < 2; ++r) { int s = r * 256 + tid; *(s16x8*)(At + s * 8) = sa[r]; }
            #pragma unroll
            for (int r = 0; r < 4; ++r) { int s = r * 256 + tid; *(s16x8*)(Bt + s * 8) = sb[r]; }
            __syncthreads();
            #pragma unroll
            for (int kk = 0; kk < BK; kk += 32) {
                s16x8 a[2], bb[4];
                #pragma unroll
                for (int fm = 0; fm < 2; ++fm)
                    a[fm] = *(const s16x8*)(At + (wm * 32 + fm * 16 + (lane & 15)) * BK + kk + (lane >> 4) * 8);
                #pragma unroll
                for (int fn = 0; fn < 4; ++fn)
                    bb[fn] = *(const s16x8*)(Bt + (wn * 64 + fn * 16 + (lane & 15)) * BK + kk + (lane >> 4) * 8);
                #pragma unroll
                for (int fm = 0; fm < 2; ++fm)
                    #pragma unroll
                    for (int fn = 0; fn < 4; ++fn)
                        acc[fm][fn] = __builtin_amdgcn_mfma_f32_16x16x32_bf16(a[fm], bb[fn], acc[fm][fn], 0, 0, 0);
            }
        }
    }
    #pragma unroll
    for (int fm = 0; fm < 2; ++fm)
        #pragma unroll
        for (int fn = 0; fn < 4; ++fn)
            #pragma unroll
            for (int r = 0; r < 4; ++r) {
                int row  = m0 + wm * 32 + fm * 16 + (lane >> 4) * 4 + r;
                int coln = n0 + wn * 64 + fn * 16 + (lane & 15);
                float v = acc[fm][fn][r];
                if (bias) v += bias[coln];
                C[(size_t)row * Nn + coln] = v;
            }
}

// ---------------- rearrange qkv -> q' (=[hi|hi|lo]) / k' (=[hi|lo|hi]) bf16 [B,H,N,192] ----------------
__global__ void k_rearrange(const float* __restrict__ qkv, unsigned short* __restrict__ qp,
                            unsigned short* __restrict__ kp) {
    int t = blockIdx.x * 256 + threadIdx.x;
    int d = t & 63, n = (t >> 6) & 1023, h = (t >> 16) & 7, b = t >> 19;
    const float* src = qkv + ((size_t)(b * N_ + n)) * (3 * D_) + h * HD_ + d;
    float q = src[0], k = src[D_];
    unsigned short qh = f2bf(q), ql = f2bf(q - bf2f(qh));
    unsigned short kh = f2bf(k), kl = f2bf(k - bf2f(kh));
    size_t base = ((size_t)(b * H_ + h) * N_ + n) * 192;
    qp[base + d] = qh; qp[base + 64 + d] = qh; qp[base + 128 + d] = ql;
    kp[base + d] = kh; kp[base + 64 + d] = kl; kp[base + 128 + d] = kh;
}

// ---------------- v -> vT bf16 [B,H,HD,N] (LDS transpose) ----------------
__global__ void k_vtrans(const float* __restrict__ qkv, unsigned short* __restrict__ vT) {
    __shared__ unsigned short T[64][65];
    int n0 = blockIdx.x * 64, h = blockIdx.y, b = blockIdx.z;
    int tid = threadIdx.x;
    #pragma unroll
    for (int rep = 0; rep < 16; ++rep) {
        int idx = rep * 256 + tid;
        int nl = idx >> 6, d = idx & 63;
        T[nl][d] = f2bf(qkv[((size_t)(b * N_ + n0 + nl)) * (3 * D_) + 2 * D_ + h * HD_ + d]);
    }
    __syncthreads();
    #pragma unroll
    for (int rep = 0; rep < 16; ++rep) {
        int idx = rep * 256 + tid;
        int dl = idx >> 6, nl = idx & 63;
        vT[((size_t)(b * H_ + h) * HD_ + dl) * N_ + n0 + nl] = T[nl][dl];
    }
}

// ---------------- pairwise MLP bias: writes alpha * bias * validmask, f32 [B,H,N,N] ----------------
// Grouped structure: runtime loop over 4 groups of 8 channels (#pragma unroll 1)
// bounds live registers structurally (~acc[8]+gg[8]+temps); no spill, no balloon.
__global__ __launch_bounds__(256) void k_bias(
    const float* __restrict__ coords, const float* __restrict__ alpha,
    const float* __restrict__ W1, const float* __restrict__ b1,
    const float* __restrict__ W2, const float* __restrict__ b2,
    float* __restrict__ biasout)
{
    __shared__ float sW1[128], sb1[32], sW2[256], sb2[8];
    int tid = threadIdx.x;
    if (tid < 128) sW1[tid] = W1[tid];
    if (tid < 32)  sb1[tid] = b1[tid];
    sW2[tid] = W2[tid];
    if (tid < 8)   sb2[tid] = b2[tid];
    __syncthreads();

    size_t t = (size_t)blockIdx.x * 256 + tid;
    int j = (int)(t & 1023), i = (int)((t >> 10) & 1023), b = (int)(t >> 20);
    const float* ci = coords + ((size_t)b * N_ + i) * 3;
    const float* cj = coords + ((size_t)b * N_ + j) * 3;
    float dx = ci[0] - cj[0], dy = ci[1] - cj[1], dz = ci[2] - cj[2];
    float dist = sqrtf(dx * dx + dy * dy + dz * dz);

    float acc[8];
    #pragma unroll
    for (int hh = 0; hh < 8; ++hh) acc[hh] = sb2[hh];

    #pragma unroll 1
    for (int g = 0; g < 4; ++g) {            // 4 groups x 8 channels; runtime loop
        float gg[8];
        #pragma unroll
        for (int cc = 0; cc < 8; ++cc) {
            int c = g * 8 + cc;
            float p = fmaf(sW1[c * 4], dx,
                      fmaf(sW1[c * 4 + 1], dy,
                      fmaf(sW1[c * 4 + 2], dz,
                      fmaf(sW1[c * 4 + 3], dist, sb1[c]))));
            gg[cc] = fast_gelu(p);
        }
        #pragma unroll
        for (int hh = 0; hh < 8; ++hh)
            #pragma unroll
            for (int cc = 0; cc < 8; ++cc)
                acc[hh] = fmaf(sW2[hh * 32 + g * 8 + cc], gg[cc], acc[hh]);
    }

    float vfac = (i >= 1 && j >= 1) ? alpha[0] : 0.f;   // NS=1 special-token zeroing + alpha fold
    #pragma unroll
    for (int hh = 0; hh < 8; ++hh)
        biasout[(((size_t)(b * H_ + hh)) * N_ + i) * N_ + j] = vfac * acc[hh];
}

// ---------------- fused attention: dots + bias + mask + softmax + attn write + PV ----------------
// 8 rows/block (slog 32.8 KB -> 4 blocks/CU for latency hiding). MFMA lanes for
// rows 8-15 duplicate rows 0-7 (harmless; stores masked to row<8).
__global__ __launch_bounds__(256) void k_attn(
    const unsigned short* __restrict__ qp, const unsigned short* __restrict__ kp,
    const unsigned short* __restrict__ vT,
    float* __restrict__ attnbuf,            // in: alpha*bias, out: attn  [B,H,N,N]
    const unsigned char* __restrict__ mraw, const int* __restrict__ flag,
    unsigned short* __restrict__ avh, unsigned short* __restrict__ avl)  // [B,N,D] hi/lo
{
    constexpr int ROWS = 8;
    constexpr int PADN = N_ + 2;            // bank-spread rows
    __shared__ float slog[ROWS * PADN];     // holds exp(l - m), unnormalized after S1
    __shared__ unsigned char smask[N_];
    __shared__ float sinv[ROWS];
    const int tid = threadIdx.x, lane = tid & 63, wid = tid >> 6;
    const int i0 = blockIdx.x * ROWS;
    const int h = blockIdx.y, b = blockIdx.z;
    const size_t bh = (size_t)(b * H_ + h);

    if (flag[0] != 0) {
        for (int i2 = tid; i2 < N_; i2 += 256) smask[i2] = mraw[b * N_ + i2];
    } else {
        const int* mi = (const int*)mraw;
        for (int i2 = tid; i2 < N_; i2 += 256) smask[i2] = (unsigned char)(mi[b * N_ + i2] != 0);
    }

    // q fragments: rows i0 + ((lane&15)&7)  (lanes 8-15 duplicate rows 0-7)
    s16x8 aq[6];
    const unsigned short* qrow = qp + (bh * N_ + i0 + ((lane & 15) & 7)) * 192 + (lane >> 4) * 8;
    #pragma unroll
    for (int ks = 0; ks < 6; ++ks) aq[ks] = *(const s16x8*)(qrow + ks * 32);
    __syncthreads();

    // ---- dots: each wave covers 16 n-tiles (256 cols) ----
    const float scale = 0.125f;            // HD^-0.5
    for (int nt = wid * 16; nt < wid * 16 + 16; ++nt) {
        f32x4 acc = {0.f, 0.f, 0.f, 0.f};
        const unsigned short* krow = kp + (bh * N_ + nt * 16 + (lane & 15)) * 192 + (lane >> 4) * 8;
        #pragma unroll
        for (int ks = 0; ks < 6; ++ks) {
            s16x8 bfrag = *(const s16x8*)(krow + ks * 32);
            acc = __builtin_amdgcn_mfma_f32_16x16x32_bf16(aq[ks], bfrag, acc, 0, 0, 0);
        }
        int col = nt * 16 + (lane & 15);
        const float* brow = attnbuf + (bh * N_ + i0) * N_ + col;
        bool mj = (smask[col] != 0);
        #pragma unroll
        for (int r = 0; r < 4; ++r) {
            int row = (lane >> 4) * 4 + r;
            if (row < ROWS) {
                float l = acc[r] * scale + brow[(size_t)row * N_];
                if (mj) l = -1e30f;
                slog[row * PADN + col] = l;
            }
        }
    }
    __syncthreads();

    // ---- softmax S1: 32 lanes per row (8 rows x 32 = 256 threads) ----
    {
        int r = wid * 2 + (lane >> 5);
        int c0 = lane & 31;
        float m = -3.4e38f;
        for (int t = 0; t < 32; ++t) m = fmaxf(m, slog[r * PADN + c0 + t * 32]);
        #pragma unroll
        for (int msk = 1; msk < 32; msk <<= 1) m = fmaxf(m, __shfl_xor(m, msk));
        float s = 0.f;
        for (int t = 0; t < 32; ++t) {
            int c = c0 + t * 32;
            float e = __expf(slog[r * PADN + c] - m);
            slog[r * PADN + c] = e;
            s += e;
        }
        #pragma unroll
        for (int msk = 1; msk < 32; msk <<= 1) s += __shfl_xor(s, msk);
        if (c0 == 0) sinv[r] = 1.0f / s;
    }
    __syncthreads();

    // ---- S2: coalesced global attn write (normalize on the fly; LDS keeps raw exp) ----
    float* gattn = attnbuf + (bh * N_ + i0) * N_;
    for (int rep = 0; rep < ROWS * 4; ++rep) {
        int idx = rep * 256 + tid;
        int r = idx >> 10, c = idx & 1023;
        gattn[(size_t)r * N_ + c] = slog[r * PADN + c] * sinv[r];
    }
    // no sync needed: PV reads S1-written slog/sinv only

    // ---- PV: wave w covers d-tile w*16; K = 1024; scale by sinv at the end ----
    {
        int d0 = wid * 16;
        f32x4 acc = {0.f, 0.f, 0.f, 0.f};
        const unsigned short* vrow = vT + (bh * HD_ + d0 + (lane & 15)) * N_ + (lane >> 4) * 8;
        for (int kk = 0; kk < N_; kk += 32) {
            int row = lane & 7, kbase = kk + (lane >> 4) * 8;
            s16x8 af;
            #pragma unroll
            for (int e = 0; e < 8; ++e) af[e] = (short)f2bf(slog[row * PADN + kbase + e]);
            s16x8 bfrag = *(const s16x8*)(vrow + kk);
            acc = __builtin_amdgcn_mfma_f32_16x16x32_bf16(af, bfrag, acc, 0, 0, 0);
        }
        #pragma unroll
        for (int r = 0; r < 4; ++r) {
            int row = (lane >> 4) * 4 + r;
            if (row < ROWS) {
                int dd = d0 + (lane & 15);
                float v = acc[r] * sinv[row];
                unsigned short hv = f2bf(v);
                size_t o = ((size_t)(b * N_) + i0 + row) * D_ + h * HD_ + dd;
                avh[o] = hv;
                avl[o] = f2bf(v - bf2f(hv));
            }
        }
    }
}

extern "C" void kernel_launch(void* const* d_in, const int* in_sizes, int n_in,
                              void* d_out, int out_size, void* d_ws, size_t ws_size,
                              hipStream_t stream) {
    (void)in_sizes; (void)n_in; (void)out_size; (void)ws_size;
    const float* x      = (const float*)d_in[0];
    const float* coords = (const float*)d_in[1];
    const unsigned char* kpm = (const unsigned char*)d_in[2];
    const float* alpha  = (const float*)d_in[3];
    const float* W1     = (const float*)d_in[4];
    const float* b1     = (const float*)d_in[5];
    const float* W2     = (const float*)d_in[6];
    const float* b2     = (const float*)d_in[7];
    const float* Wqkv   = (const float*)d_in[8];
    const float* Wout   = (const float*)d_in[9];
    const float* bout   = (const float*)d_in[10];

    float* out  = (float*)d_out;                     // [B,N,D] = [4096,512]
    float* attn = out + (size_t)B_ * N_ * D_;        // [B,H,N,N] (also bias staging)

    // ---- workspace carve ----
    char* w = (char*)d_ws;
    auto alloc = [&](size_t bytes) { char* p = w; w += (bytes + 255) & ~(size_t)255; return p; };
    const size_t SZ_X  = (size_t)B_ * N_ * D_;       // 2,097,152
    const size_t SZ_WQ = (size_t)3 * D_ * D_;        // 786,432
    const size_t SZ_WO = (size_t)D_ * D_;            // 262,144
    unsigned short* x_hi = (unsigned short*)alloc(SZ_X * 2);
    unsigned short* x_lo = (unsigned short*)alloc(SZ_X * 2);
    unsigned short* wq_hi = (unsigned short*)alloc(SZ_WQ * 2);
    unsigned short* wq_lo = (unsigned short*)alloc(SZ_WQ * 2);
    unsigned short* wo_hi = (unsigned short*)alloc(SZ_WO * 2);
    unsigned short* wo_lo = (unsigned short*)alloc(SZ_WO * 2);
    float* qkv = (float*)alloc((size_t)B_ * N_ * 3 * D_ * 4);           // 25.2 MB
    unsigned short* qp = (unsigned short*)alloc((size_t)B_ * H_ * N_ * 192 * 2);
    unsigned short* kp = (unsigned short*)alloc((size_t)B_ * H_ * N_ * 192 * 2);
    unsigned short* vT = (unsigned short*)alloc((size_t)B_ * H_ * HD_ * N_ * 2);
    unsigned short* av_hi = (unsigned short*)alloc(SZ_X * 2);
    unsigned short* av_lo = (unsigned short*)alloc(SZ_X * 2);
    int* flag = (int*)alloc(256);

    // 1. splits
    k_split<<<(int)((SZ_X + 255) / 256), 256, 0, stream>>>(x, x_hi, x_lo, (int)SZ_X);
    k_split<<<(int)((SZ_WQ + 255) / 256), 256, 0, stream>>>(Wqkv, wq_hi, wq_lo, (int)SZ_WQ);
    k_split<<<(int)((SZ_WO + 255) / 256), 256, 0, stream>>>(Wout, wo_hi, wo_lo, (int)SZ_WO);
    // 2. mask layout detect
    k_mask_detect<<<1, 256, 0, stream>>>(kpm, flag);
    // 3. qkv projection: [4096,1536] = x[4096,512] @ Wqkv[1536,512]^T
    k_gemm3<<<dim3(64, 12), 256, 0, stream>>>(x_hi, x_lo, wq_hi, wq_lo, qkv, nullptr,
                                              B_ * N_, 3 * D_, D_);
    // 4. rearrange q', k', vT
    k_rearrange<<<(B_ * H_ * N_ * HD_) / 256, 256, 0, stream>>>(qkv, qp, kp);
    k_vtrans<<<dim3(16, H_, B_), 256, 0, stream>>>(qkv, vT);
    // 5. pairwise MLP bias -> attn region of d_out
    k_bias<<<(B_ * N_ * N_) / 256, 256, 0, stream>>>(coords, alpha, W1, b1, W2, b2, attn);
    // 6. fused attention (reads bias from attn region, overwrites with attn)
    k_attn<<<dim3(128, H_, B_), 256, 0, stream>>>(qp, kp, vT, attn, kpm, flag, av_hi, av_lo);
    // 7. output projection: out[4096,512] = av[4096,512] @ Wout[512,512]^T + bout
    k_gemm3<<<dim3(64, 4), 256, 0, stream>>>(av_hi, av_lo, wo_hi, wo_lo, out, bout,
                                             B_ * N_, D_, D_);
}

// Round 8
// 358.812 us; speedup vs baseline: 1.3739x; 1.3739x over previous
//
#include <hip/hip_runtime.h>
#include <stdint.h>
#include <math.h>

#define B_  4
#define N_  1024
#define D_  512
#define H_  8
#define HD_ 64

typedef short s16x8 __attribute__((ext_vector_type(8)));
typedef float f32x4 __attribute__((ext_vector_type(4)));

__device__ __forceinline__ unsigned short f2bf(float f) {
    unsigned u = __float_as_uint(f);
    u += 0x7fffu + ((u >> 16) & 1u);      // RNE
    return (unsigned short)(u >> 16);
}
__device__ __forceinline__ float bf2f(unsigned short h) {
    return __uint_as_float(((unsigned)h) << 16);
}

// fast exact-erf gelu: A&S 7.1.26 rational, |erf err| <= 1.5e-7, branch-free
__device__ __forceinline__ float fast_gelu(float x) {
    float ax = fabsf(x) * 0.7071067811865476f;          // |x|/sqrt(2)
    float t  = __builtin_amdgcn_rcpf(fmaf(0.3275911f, ax, 1.0f));
    float e  = __expf(-ax * ax);
    float poly = t * fmaf(t, fmaf(t, fmaf(t, fmaf(t, 1.061405429f, -1.453152027f),
                                          1.421413741f), -0.284496736f), 0.254829592f);
    float erfv = 1.0f - poly * e;                        // erf(|x|/sqrt2)
    float s = copysignf(erfv, x);
    return 0.5f * x * (1.0f + s);
}

// ---------------- split f32 -> (hi, lo) bf16 ----------------
__global__ void k_split(const float* __restrict__ s, unsigned short* __restrict__ h,
                        unsigned short* __restrict__ l, int n) {
    int i = blockIdx.x * 256 + threadIdx.x;
    if (i < n) {
        float x = s[i];
        unsigned short hb = f2bf(x);
        h[i] = hb;
        l[i] = f2bf(x - bf2f(hb));
    }
}

// ---------------- mask layout detection ----------------
__global__ void k_mask_detect(const unsigned char* __restrict__ m, int* __restrict__ flag) {
    __shared__ int s;
    if (threadIdx.x == 0) s = 0;
    __syncthreads();
    int found = 0;
    for (int i = threadIdx.x; i < B_ * N_; i += 256)
        if ((i & 3) && m[i]) found = 1;
    if (found) atomicOr(&s, 1);
    __syncthreads();
    if (threadIdx.x == 0) flag[0] = s;
}

// ---------------- split-bf16 GEMM: C[M,N] = A[M,K] @ B[N,K]^T (+bias) ----------------
__global__ __launch_bounds__(256) void k_gemm3(
    const unsigned short* __restrict__ Ah, const unsigned short* __restrict__ Al,
    const unsigned short* __restrict__ Bwh, const unsigned short* __restrict__ Bwl,
    float* __restrict__ C, const float* __restrict__ bias, int M, int Nn, int K)
{
    constexpr int BM = 64, BN = 128, BK = 64;
    __shared__ unsigned short At[BM * BK];
    __shared__ unsigned short Bt[BN * BK];
    const int tid = threadIdx.x, lane = tid & 63, wid = tid >> 6;
    const int m0 = blockIdx.x * BM, n0 = blockIdx.y * BN;
    const int wm = wid >> 1, wn = wid & 1;   // wave tile: 32 rows x 64 cols
    f32x4 acc[2][4] = {};
    const unsigned short* Aps[3] = {Ah, Ah, Al};
    const unsigned short* Bps[3] = {Bwh, Bwl, Bwh};

    for (int combo = 0; combo < 3; ++combo) {
        const unsigned short* __restrict__ Ap = Aps[combo];
        const unsigned short* __restrict__ Bp = Bps[combo];
        for (int k0 = 0; k0 < K; k0 += BK) {
            s16x8 sa[2], sb[4];
            #pragma unroll
            for (int r = 0; r < 2; ++r) {
                int s = r * 256 + tid, row = s >> 3, c8 = s & 7;
                sa[r] = *(const s16x8*)(Ap + (size_t)(m0 + row) * K + k0 + c8 * 8);
            }
            #pragma unroll
            for (int r = 0; r < 4; ++r) {
                int s = r * 256 + tid, row = s >> 3, c8 = s & 7;
                sb[r] = *(const s16x8*)(Bp + (size_t)(n0 + row) * K + k0 + c8 * 8);
            }
            __syncthreads();  // previous-iter LDS reads done
            #pragma unroll
            for (int r = 0; r < 2; ++r) { int s = r * 256 + tid; *(s16x8*)(At + s * 8) = sa[r]; }
            #pragma unroll
            for (int r = 0; r < 4; ++r) { int s = r * 256 + tid; *(s16x8*)(Bt + s * 8) = sb[r]; }
            __syncthreads();
            #pragma unroll
            for (int kk = 0; kk < BK; kk += 32) {
                s16x8 a[2], bb[4];
                #pragma unroll
                for (int fm = 0; fm < 2; ++fm)
                    a[fm] = *(const s16x8*)(At + (wm * 32 + fm * 16 + (lane & 15)) * BK + kk + (lane >> 4) * 8);
                #pragma unroll
                for (int fn = 0; fn < 4; ++fn)
                    bb[fn] = *(const s16x8*)(Bt + (wn * 64 + fn * 16 + (lane & 15)) * BK + kk + (lane >> 4) * 8);
                #pragma unroll
                for (int fm = 0; fm < 2; ++fm)
                    #pragma unroll
                    for (int fn = 0; fn < 4; ++fn)
                        acc[fm][fn] = __builtin_amdgcn_mfma_f32_16x16x32_bf16(a[fm], bb[fn], acc[fm][fn], 0, 0, 0);
            }
        }
    }
    #pragma unroll
    for (int fm = 0; fm < 2; ++fm)
        #pragma unroll
        for (int fn = 0; fn < 4; ++fn)
            #pragma unroll
            for (int r = 0; r < 4; ++r) {
                int row  = m0 + wm * 32 + fm * 16 + (lane >> 4) * 4 + r;
                int coln = n0 + wn * 64 + fn * 16 + (lane & 15);
                float v = acc[fm][fn][r];
                if (bias) v += bias[coln];
                C[(size_t)row * Nn + coln] = v;
            }
}

// ---------------- rearrange qkv -> q' (=[hi|hi|lo]) / k' (=[hi|lo|hi]) bf16 [B,H,N,192] ----------------
__global__ void k_rearrange(const float* __restrict__ qkv, unsigned short* __restrict__ qp,
                            unsigned short* __restrict__ kp) {
    int t = blockIdx.x * 256 + threadIdx.x;
    int d = t & 63, n = (t >> 6) & 1023, h = (t >> 16) & 7, b = t >> 19;
    const float* src = qkv + ((size_t)(b * N_ + n)) * (3 * D_) + h * HD_ + d;
    float q = src[0], k = src[D_];
    unsigned short qh = f2bf(q), ql = f2bf(q - bf2f(qh));
    unsigned short kh = f2bf(k), kl = f2bf(k - bf2f(kh));
    size_t base = ((size_t)(b * H_ + h) * N_ + n) * 192;
    qp[base + d] = qh; qp[base + 64 + d] = qh; qp[base + 128 + d] = ql;
    kp[base + d] = kh; kp[base + 64 + d] = kl; kp[base + 128 + d] = kh;
}

// ---------------- v -> vT bf16 [B,H,HD,N] (LDS transpose) ----------------
__global__ void k_vtrans(const float* __restrict__ qkv, unsigned short* __restrict__ vT) {
    __shared__ unsigned short T[64][65];
    int n0 = blockIdx.x * 64, h = blockIdx.y, b = blockIdx.z;
    int tid = threadIdx.x;
    #pragma unroll
    for (int rep = 0; rep < 16; ++rep) {
        int idx = rep * 256 + tid;
        int nl = idx >> 6, d = idx & 63;
        T[nl][d] = f2bf(qkv[((size_t)(b * N_ + n0 + nl)) * (3 * D_) + 2 * D_ + h * HD_ + d]);
    }
    __syncthreads();
    #pragma unroll
    for (int rep = 0; rep < 16; ++rep) {
        int idx = rep * 256 + tid;
        int dl = idx >> 6, nl = idx & 63;
        vT[((size_t)(b * H_ + h) * HD_ + dl) * N_ + n0 + nl] = T[nl][dl];
    }
}

// ---------------- pairwise MLP bias: writes alpha * bias * validmask, f32 [B,H,N,N] ----------------
// Grouped structure: runtime loop over 4 groups of 8 channels (#pragma unroll 1)
// bounds live registers structurally (~acc[8]+gg[8]+temps); no spill, no balloon.
__global__ __launch_bounds__(256) void k_bias(
    const float* __restrict__ coords, const float* __restrict__ alpha,
    const float* __restrict__ W1, const float* __restrict__ b1,
    const float* __restrict__ W2, const float* __restrict__ b2,
    float* __restrict__ biasout)
{
    __shared__ float sW1[128], sb1[32], sW2[256], sb2[8];
    int tid = threadIdx.x;
    if (tid < 128) sW1[tid] = W1[tid];
    if (tid < 32)  sb1[tid] = b1[tid];
    sW2[tid] = W2[tid];
    if (tid < 8)   sb2[tid] = b2[tid];
    __syncthreads();

    size_t t = (size_t)blockIdx.x * 256 + tid;
    int j = (int)(t & 1023), i = (int)((t >> 10) & 1023), b = (int)(t >> 20);
    const float* ci = coords + ((size_t)b * N_ + i) * 3;
    const float* cj = coords + ((size_t)b * N_ + j) * 3;
    float dx = ci[0] - cj[0], dy = ci[1] - cj[1], dz = ci[2] - cj[2];
    float dist = sqrtf(dx * dx + dy * dy + dz * dz);

    float acc[8];
    #pragma unroll
    for (int hh = 0; hh < 8; ++hh) acc[hh] = sb2[hh];

    #pragma unroll 1
    for (int g = 0; g < 4; ++g) {            // 4 groups x 8 channels; runtime loop
        float gg[8];
        #pragma unroll
        for (int cc = 0; cc < 8; ++cc) {
            int c = g * 8 + cc;
            float p = fmaf(sW1[c * 4], dx,
                      fmaf(sW1[c * 4 + 1], dy,
                      fmaf(sW1[c * 4 + 2], dz,
                      fmaf(sW1[c * 4 + 3], dist, sb1[c]))));
            gg[cc] = fast_gelu(p);
        }
        #pragma unroll
        for (int hh = 0; hh < 8; ++hh)
            #pragma unroll
            for (int cc = 0; cc < 8; ++cc)
                acc[hh] = fmaf(sW2[hh * 32 + g * 8 + cc], gg[cc], acc[hh]);
    }

    float vfac = (i >= 1 && j >= 1) ? alpha[0] : 0.f;   // NS=1 special-token zeroing + alpha fold
    #pragma unroll
    for (int hh = 0; hh < 8; ++hh)
        biasout[(((size_t)(b * H_ + hh)) * N_ + i) * N_ + j] = vfac * acc[hh];
}

// ---------------- fused attention: dots + bias + mask + softmax + attn write + PV ----------------
// 16 rows/block. Bias tile register-prefetched (coalesced f32x4), added after dots.
// S2 vectorized f32x4 normalize+store; PV consumes raw exp, scales by sinv.
__global__ __launch_bounds__(256) void k_attn(
    const unsigned short* __restrict__ qp, const unsigned short* __restrict__ kp,
    const unsigned short* __restrict__ vT,
    float* __restrict__ attnbuf,            // in: alpha*bias, out: attn  [B,H,N,N]
    const unsigned char* __restrict__ mraw, const int* __restrict__ flag,
    unsigned short* __restrict__ avh, unsigned short* __restrict__ avl)  // [B,N,D] hi/lo
{
    constexpr int PADN = N_ + 4;            // 1028: 16B-aligned rows, 4-bank row skew
    __shared__ float slog[16 * PADN];
    __shared__ unsigned char smask[N_];
    __shared__ float sinv[16];
    const int tid = threadIdx.x, lane = tid & 63, wid = tid >> 6;
    const int i0 = blockIdx.x * 16;
    const int h = blockIdx.y, b = blockIdx.z;
    const size_t bh = (size_t)(b * H_ + h);

    // ---- prefetch bias tile 16x1024 into registers, fully coalesced ----
    f32x4 breg[16];
    const float* bbase = attnbuf + (bh * N_ + i0) * N_;
    #pragma unroll
    for (int kb = 0; kb < 16; ++kb)
        breg[kb] = *(const f32x4*)(bbase + (size_t)kb * 1024 + tid * 4);

    if (flag[0] != 0) {
        for (int i2 = tid; i2 < N_; i2 += 256) smask[i2] = mraw[b * N_ + i2];
    } else {
        const int* mi = (const int*)mraw;
        for (int i2 = tid; i2 < N_; i2 += 256) smask[i2] = (unsigned char)(mi[b * N_ + i2] != 0);
    }

    // q fragments: rows i0+(lane&15), K'=192 (6 k-steps of 32)
    s16x8 aq[6];
    const unsigned short* qrow = qp + (bh * N_ + i0 + (lane & 15)) * 192 + (lane >> 4) * 8;
    #pragma unroll
    for (int ks = 0; ks < 6; ++ks) aq[ks] = *(const s16x8*)(qrow + ks * 32);
    __syncthreads();

    // ---- dots: raw dots*scale into slog (bias/mask applied later from registers) ----
    const float scale = 0.125f;            // HD^-0.5
    for (int nt = wid * 16; nt < wid * 16 + 16; ++nt) {
        f32x4 acc = {0.f, 0.f, 0.f, 0.f};
        const unsigned short* krow = kp + (bh * N_ + nt * 16 + (lane & 15)) * 192 + (lane >> 4) * 8;
        #pragma unroll
        for (int ks = 0; ks < 6; ++ks) {
            s16x8 bfrag = *(const s16x8*)(krow + ks * 32);
            acc = __builtin_amdgcn_mfma_f32_16x16x32_bf16(aq[ks], bfrag, acc, 0, 0, 0);
        }
        int col = nt * 16 + (lane & 15);
        #pragma unroll
        for (int r = 0; r < 4; ++r) {
            int row = (lane >> 4) * 4 + r;
            slog[row * PADN + col] = acc[r] * scale;
        }
    }
    __syncthreads();

    // ---- bias add + mask (row kb handled by all 256 threads: c4 = tid*4) ----
    #pragma unroll
    for (int kb = 0; kb < 16; ++kb) {
        int c4 = tid * 4;
        f32x4 v = *(const f32x4*)(slog + kb * PADN + c4);
        f32x4 bv = breg[kb];
        #pragma unroll
        for (int e = 0; e < 4; ++e) {
            float l = v[e] + bv[e];
            if (smask[c4 + e]) l = -1e30f;
            v[e] = l;
        }
        *(f32x4*)(slog + kb * PADN + c4) = v;
    }
    __syncthreads();

    // ---- softmax S1: wave w owns rows w*4+(lane>>4); 16 lanes per row ----
    {
        int r = wid * 4 + (lane >> 4);
        int c0 = lane & 15;
        float m = -3.4e38f;
        for (int t = 0; t < 64; ++t) m = fmaxf(m, slog[r * PADN + c0 + t * 16]);
        #pragma unroll
        for (int msk = 1; msk < 16; msk <<= 1) m = fmaxf(m, __shfl_xor(m, msk));
        float s = 0.f;
        for (int t = 0; t < 64; ++t) {
            int c = c0 + t * 16;
            float e = __expf(slog[r * PADN + c] - m);
            slog[r * PADN + c] = e;
            s += e;
        }
        #pragma unroll
        for (int msk = 1; msk < 16; msk <<= 1) s += __shfl_xor(s, msk);
        if (c0 == 0) sinv[r] = 1.0f / s;
    }
    __syncthreads();

    // ---- S2: vectorized normalized global attn write (LDS keeps raw exp) ----
    float* gattn = attnbuf + (bh * N_ + i0) * N_;
    #pragma unroll
    for (int rep = 0; rep < 16; ++rep) {
        int c4 = tid * 4;
        f32x4 v = *(const f32x4*)(slog + rep * PADN + c4);
        float si = sinv[rep];
        v[0] *= si; v[1] *= si; v[2] *= si; v[3] *= si;
        *(f32x4*)(gattn + (size_t)rep * N_ + c4) = v;
    }
    // no sync needed: PV reads S1-written slog/sinv only

    // ---- PV: wave w covers d-tile w*16; K = 1024; scale by sinv at the end ----
    {
        int d0 = wid * 16;
        f32x4 acc = {0.f, 0.f, 0.f, 0.f};
        const unsigned short* vrow = vT + (bh * HD_ + d0 + (lane & 15)) * N_ + (lane >> 4) * 8;
        for (int kk = 0; kk < N_; kk += 32) {
            s16x8 bfrag = *(const s16x8*)(vrow + kk);   // issue global load first
            int row = lane & 15, kbase = kk + (lane >> 4) * 8;
            s16x8 af;
            #pragma unroll
            for (int e = 0; e < 8; ++e) af[e] = (short)f2bf(slog[row * PADN + kbase + e]);
            acc = __builtin_amdgcn_mfma_f32_16x16x32_bf16(af, bfrag, acc, 0, 0, 0);
        }
        #pragma unroll
        for (int r = 0; r < 4; ++r) {
            int row = (lane >> 4) * 4 + r;
            int dd = d0 + (lane & 15);
            float v = acc[r] * sinv[row];
            unsigned short hv = f2bf(v);
            size_t o = ((size_t)(b * N_) + i0 + row) * D_ + h * HD_ + dd;
            avh[o] = hv;
            avl[o] = f2bf(v - bf2f(hv));
        }
    }
}

extern "C" void kernel_launch(void* const* d_in, const int* in_sizes, int n_in,
                              void* d_out, int out_size, void* d_ws, size_t ws_size,
                              hipStream_t stream) {
    (void)in_sizes; (void)n_in; (void)out_size; (void)ws_size;
    const float* x      = (const float*)d_in[0];
    const float* coords = (const float*)d_in[1];
    const unsigned char* kpm = (const unsigned char*)d_in[2];
    const float* alpha  = (const float*)d_in[3];
    const float* W1     = (const float*)d_in[4];
    const float* b1     = (const float*)d_in[5];
    const float* W2     = (const float*)d_in[6];
    const float* b2     = (const float*)d_in[7];
    const float* Wqkv   = (const float*)d_in[8];
    const float* Wout   = (const float*)d_in[9];
    const float* bout   = (const float*)d_in[10];

    float* out  = (float*)d_out;                     // [B,N,D] = [4096,512]
    float* attn = out + (size_t)B_ * N_ * D_;        // [B,H,N,N] (also bias staging)

    // ---- workspace carve ----
    char* w = (char*)d_ws;
    auto alloc = [&](size_t bytes) { char* p = w; w += (bytes + 255) & ~(size_t)255; return p; };
    const size_t SZ_X  = (size_t)B_ * N_ * D_;       // 2,097,152
    const size_t SZ_WQ = (size_t)3 * D_ * D_;        // 786,432
    const size_t SZ_WO = (size_t)D_ * D_;            // 262,144
    unsigned short* x_hi = (unsigned short*)alloc(SZ_X * 2);
    unsigned short* x_lo = (unsigned short*)alloc(SZ_X * 2);
    unsigned short* wq_hi = (unsigned short*)alloc(SZ_WQ * 2);
    unsigned short* wq_lo = (unsigned short*)alloc(SZ_WQ * 2);
    unsigned short* wo_hi = (unsigned short*)alloc(SZ_WO * 2);
    unsigned short* wo_lo = (unsigned short*)alloc(SZ_WO * 2);
    float* qkv = (float*)alloc((size_t)B_ * N_ * 3 * D_ * 4);           // 25.2 MB
    unsigned short* qp = (unsigned short*)alloc((size_t)B_ * H_ * N_ * 192 * 2);
    unsigned short* kp = (unsigned short*)alloc((size_t)B_ * H_ * N_ * 192 * 2);
    unsigned short* vT = (unsigned short*)alloc((size_t)B_ * H_ * HD_ * N_ * 2);
    unsigned short* av_hi = (unsigned short*)alloc(SZ_X * 2);
    unsigned short* av_lo = (unsigned short*)alloc(SZ_X * 2);
    int* flag = (int*)alloc(256);

    // 1. splits
    k_split<<<(int)((SZ_X + 255) / 256), 256, 0, stream>>>(x, x_hi, x_lo, (int)SZ_X);
    k_split<<<(int)((SZ_WQ + 255) / 256), 256, 0, stream>>>(Wqkv, wq_hi, wq_lo, (int)SZ_WQ);
    k_split<<<(int)((SZ_WO + 255) / 256), 256, 0, stream>>>(Wout, wo_hi, wo_lo, (int)SZ_WO);
    // 2. mask layout detect
    k_mask_detect<<<1, 256, 0, stream>>>(kpm, flag);
    // 3. qkv projection: [4096,1536] = x[4096,512] @ Wqkv[1536,512]^T
    k_gemm3<<<dim3(64, 12), 256, 0, stream>>>(x_hi, x_lo, wq_hi, wq_lo, qkv, nullptr,
                                              B_ * N_, 3 * D_, D_);
    // 4. rearrange q', k', vT
    k_rearrange<<<(B_ * H_ * N_ * HD_) / 256, 256, 0, stream>>>(qkv, qp, kp);
    k_vtrans<<<dim3(16, H_, B_), 256, 0, stream>>>(qkv, vT);
    // 5. pairwise MLP bias -> attn region of d_out
    k_bias<<<(B_ * N_ * N_) / 256, 256, 0, stream>>>(coords, alpha, W1, b1, W2, b2, attn);
    // 6. fused attention (reads bias from attn region, overwrites with attn)
    k_attn<<<dim3(64, H_, B_), 256, 0, stream>>>(qp, kp, vT, attn, kpm, flag, av_hi, av_lo);
    // 7. output projection: out[4096,512] = av[4096,512] @ Wout[512,512]^T + bout
    k_gemm3<<<dim3(64, 4), 256, 0, stream>>>(av_hi, av_lo, wo_hi, wo_lo, out, bout,
                                             B_ * N_, D_, D_);
}

// Round 9
// 347.666 us; speedup vs baseline: 1.4179x; 1.0321x over previous
//
#include <hip/hip_runtime.h>
#include <stdint.h>
#include <math.h>

#define B_  4
#define N_  1024
#define D_  512
#define H_  8
#define HD_ 64

typedef short s16x8 __attribute__((ext_vector_type(8)));
typedef float f32x4 __attribute__((ext_vector_type(4)));

__device__ __forceinline__ unsigned short f2bf(float f) {
    unsigned u = __float_as_uint(f);
    u += 0x7fffu + ((u >> 16) & 1u);      // RNE
    return (unsigned short)(u >> 16);
}
__device__ __forceinline__ float bf2f(unsigned short h) {
    return __uint_as_float(((unsigned)h) << 16);
}

// fast exact-erf gelu: A&S 7.1.26 rational, |erf err| <= 1.5e-7, branch-free
__device__ __forceinline__ float fast_gelu(float x) {
    float ax = fabsf(x) * 0.7071067811865476f;          // |x|/sqrt(2)
    float t  = __builtin_amdgcn_rcpf(fmaf(0.3275911f, ax, 1.0f));
    float e  = __expf(-ax * ax);
    float poly = t * fmaf(t, fmaf(t, fmaf(t, fmaf(t, 1.061405429f, -1.453152027f),
                                          1.421413741f), -0.284496736f), 0.254829592f);
    float erfv = 1.0f - poly * e;                        // erf(|x|/sqrt2)
    float s = copysignf(erfv, x);
    return 0.5f * x * (1.0f + s);
}

// ---------------- split f32 -> (hi, lo) bf16 ----------------
__global__ void k_split(const float* __restrict__ s, unsigned short* __restrict__ h,
                        unsigned short* __restrict__ l, int n) {
    int i = blockIdx.x * 256 + threadIdx.x;
    if (i < n) {
        float x = s[i];
        unsigned short hb = f2bf(x);
        h[i] = hb;
        l[i] = f2bf(x - bf2f(hb));
    }
}

// ---------------- mask layout detection ----------------
__global__ void k_mask_detect(const unsigned char* __restrict__ m, int* __restrict__ flag) {
    __shared__ int s;
    if (threadIdx.x == 0) s = 0;
    __syncthreads();
    int found = 0;
    for (int i = threadIdx.x; i < B_ * N_; i += 256)
        if ((i & 3) && m[i]) found = 1;
    if (found) atomicOr(&s, 1);
    __syncthreads();
    if (threadIdx.x == 0) flag[0] = s;
}

// ---------------- split-bf16 GEMM: C[M,N] = A[M,K] @ B[N,K]^T (+bias) ----------------
__global__ __launch_bounds__(256) void k_gemm3(
    const unsigned short* __restrict__ Ah, const unsigned short* __restrict__ Al,
    const unsigned short* __restrict__ Bwh, const unsigned short* __restrict__ Bwl,
    float* __restrict__ C, const float* __restrict__ bias, int M, int Nn, int K)
{
    constexpr int BM = 64, BN = 128, BK = 64;
    __shared__ unsigned short At[BM * BK];
    __shared__ unsigned short Bt[BN * BK];
    const int tid = threadIdx.x, lane = tid & 63, wid = tid >> 6;
    const int m0 = blockIdx.x * BM, n0 = blockIdx.y * BN;
    const int wm = wid >> 1, wn = wid & 1;   // wave tile: 32 rows x 64 cols
    f32x4 acc[2][4] = {};
    const unsigned short* Aps[3] = {Ah, Ah, Al};
    const unsigned short* Bps[3] = {Bwh, Bwl, Bwh};

    for (int combo = 0; combo < 3; ++combo) {
        const unsigned short* __restrict__ Ap = Aps[combo];
        const unsigned short* __restrict__ Bp = Bps[combo];
        for (int k0 = 0; k0 < K; k0 += BK) {
            s16x8 sa[2], sb[4];
            #pragma unroll
            for (int r = 0; r < 2; ++r) {
                int s = r * 256 + tid, row = s >> 3, c8 = s & 7;
                sa[r] = *(const s16x8*)(Ap + (size_t)(m0 + row) * K + k0 + c8 * 8);
            }
            #pragma unroll
            for (int r = 0; r < 4; ++r) {
                int s = r * 256 + tid, row = s >> 3, c8 = s & 7;
                sb[r] = *(const s16x8*)(Bp + (size_t)(n0 + row) * K + k0 + c8 * 8);
            }
            __syncthreads();  // previous-iter LDS reads done
            #pragma unroll
            for (int r = 0; r < 2; ++r) { int s = r * 256 + tid; *(s16x8*)(At + s * 8) = sa[r]; }
            #pragma unroll
            for (int r = 0; r < 4; ++r) { int s = r * 256 + tid; *(s16x8*)(Bt + s * 8) = sb[r]; }
            __syncthreads();
            #pragma unroll
            for (int kk = 0; kk < BK; kk += 32) {
                s16x8 a[2], bb[4];
                #pragma unroll
                for (int fm = 0; fm < 2; ++fm)
                    a[fm] = *(const s16x8*)(At + (wm * 32 + fm * 16 + (lane & 15)) * BK + kk + (lane >> 4) * 8);
                #pragma unroll
                for (int fn = 0; fn < 4; ++fn)
                    bb[fn] = *(const s16x8*)(Bt + (wn * 64 + fn * 16 + (lane & 15)) * BK + kk + (lane >> 4) * 8);
                #pragma unroll
                for (int fm = 0; fm < 2; ++fm)
                    #pragma unroll
                    for (int fn = 0; fn < 4; ++fn)
                        acc[fm][fn] = __builtin_amdgcn_mfma_f32_16x16x32_bf16(a[fm], bb[fn], acc[fm][fn], 0, 0, 0);
            }
        }
    }
    #pragma unroll
    for (int fm = 0; fm < 2; ++fm)
        #pragma unroll
        for (int fn = 0; fn < 4; ++fn)
            #pragma unroll
            for (int r = 0; r < 4; ++r) {
                int row  = m0 + wm * 32 + fm * 16 + (lane >> 4) * 4 + r;
                int coln = n0 + wn * 64 + fn * 16 + (lane & 15);
                float v = acc[fm][fn][r];
                if (bias) v += bias[coln];
                C[(size_t)row * Nn + coln] = v;
            }
}

// ---------------- rearrange qkv -> q' (=[hi|hi|lo]) / k' (=[hi|lo|hi]) bf16 [B,H,N,192] ----------------
__global__ void k_rearrange(const float* __restrict__ qkv, unsigned short* __restrict__ qp,
                            unsigned short* __restrict__ kp) {
    int t = blockIdx.x * 256 + threadIdx.x;
    int d = t & 63, n = (t >> 6) & 1023, h = (t >> 16) & 7, b = t >> 19;
    const float* src = qkv + ((size_t)(b * N_ + n)) * (3 * D_) + h * HD_ + d;
    float q = src[0], k = src[D_];
    unsigned short qh = f2bf(q), ql = f2bf(q - bf2f(qh));
    unsigned short kh = f2bf(k), kl = f2bf(k - bf2f(kh));
    size_t base = ((size_t)(b * H_ + h) * N_ + n) * 192;
    qp[base + d] = qh; qp[base + 64 + d] = qh; qp[base + 128 + d] = ql;
    kp[base + d] = kh; kp[base + 64 + d] = kl; kp[base + 128 + d] = kh;
}

// ---------------- v -> vT bf16 [B,H,HD,N] (LDS transpose) ----------------
__global__ void k_vtrans(const float* __restrict__ qkv, unsigned short* __restrict__ vT) {
    __shared__ unsigned short T[64][65];
    int n0 = blockIdx.x * 64, h = blockIdx.y, b = blockIdx.z;
    int tid = threadIdx.x;
    #pragma unroll
    for (int rep = 0; rep < 16; ++rep) {
        int idx = rep * 256 + tid;
        int nl = idx >> 6, d = idx & 63;
        T[nl][d] = f2bf(qkv[((size_t)(b * N_ + n0 + nl)) * (3 * D_) + 2 * D_ + h * HD_ + d]);
    }
    __syncthreads();
    #pragma unroll
    for (int rep = 0; rep < 16; ++rep) {
        int idx = rep * 256 + tid;
        int dl = idx >> 6, nl = idx & 63;
        vT[((size_t)(b * H_ + h) * HD_ + dl) * N_ + n0 + nl] = T[nl][dl];
    }
}

// ---------------- pairwise MLP bias: writes alpha * bias * validmask, f32 [B,H,N,N] ----------------
// Grouped structure: runtime loop over 4 groups of 8 channels (#pragma unroll 1)
// bounds live registers structurally (~acc[8]+gg[8]+temps); no spill, no balloon.
__global__ __launch_bounds__(256) void k_bias(
    const float* __restrict__ coords, const float* __restrict__ alpha,
    const float* __restrict__ W1, const float* __restrict__ b1,
    const float* __restrict__ W2, const float* __restrict__ b2,
    float* __restrict__ biasout)
{
    __shared__ float sW1[128], sb1[32], sW2[256], sb2[8];
    int tid = threadIdx.x;
    if (tid < 128) sW1[tid] = W1[tid];
    if (tid < 32)  sb1[tid] = b1[tid];
    sW2[tid] = W2[tid];
    if (tid < 8)   sb2[tid] = b2[tid];
    __syncthreads();

    size_t t = (size_t)blockIdx.x * 256 + tid;
    int j = (int)(t & 1023), i = (int)((t >> 10) & 1023), b = (int)(t >> 20);
    const float* ci = coords + ((size_t)b * N_ + i) * 3;
    const float* cj = coords + ((size_t)b * N_ + j) * 3;
    float dx = ci[0] - cj[0], dy = ci[1] - cj[1], dz = ci[2] - cj[2];
    float dist = sqrtf(dx * dx + dy * dy + dz * dz);

    float acc[8];
    #pragma unroll
    for (int hh = 0; hh < 8; ++hh) acc[hh] = sb2[hh];

    #pragma unroll 1
    for (int g = 0; g < 4; ++g) {            // 4 groups x 8 channels; runtime loop
        float gg[8];
        #pragma unroll
        for (int cc = 0; cc < 8; ++cc) {
            int c = g * 8 + cc;
            float p = fmaf(sW1[c * 4], dx,
                      fmaf(sW1[c * 4 + 1], dy,
                      fmaf(sW1[c * 4 + 2], dz,
                      fmaf(sW1[c * 4 + 3], dist, sb1[c]))));
            gg[cc] = fast_gelu(p);
        }
        #pragma unroll
        for (int hh = 0; hh < 8; ++hh)
            #pragma unroll
            for (int cc = 0; cc < 8; ++cc)
                acc[hh] = fmaf(sW2[hh * 32 + g * 8 + cc], gg[cc], acc[hh]);
    }

    float vfac = (i >= 1 && j >= 1) ? alpha[0] : 0.f;   // NS=1 special-token zeroing + alpha fold
    #pragma unroll
    for (int hh = 0; hh < 8; ++hh)
        biasout[(((size_t)(b * H_ + hh)) * N_ + i) * N_ + j] = vfac * acc[hh];
}

// ---------------- fused attention, register-resident logits ----------------
// 16 rows/block, 4 waves; wave w owns cols [w*256, w*256+256). Logits live in
// acc[16] f32x4 (statically indexed). Softmax via regs + shfl + tiny LDS reduce.
// Only big LDS: P (bf16 exp, 16x1024, XOR-swizzled) feeding PV ds_read_b128.
__global__ __launch_bounds__(256) void k_attn(
    const unsigned short* __restrict__ qp, const unsigned short* __restrict__ kp,
    const unsigned short* __restrict__ vT,
    float* __restrict__ attnbuf,            // in: alpha*bias, out: attn  [B,H,N,N]
    const unsigned char* __restrict__ mraw, const int* __restrict__ flag,
    unsigned short* __restrict__ avh, unsigned short* __restrict__ avl)  // [B,N,D] hi/lo
{
    __shared__ unsigned short P[16 * 1024];   // 32 KB, swizzled: byte ^= (row&7)<<4
    __shared__ unsigned char smask[N_];
    __shared__ float redm[16][4];
    __shared__ float reds[16][4];
    const int tid = threadIdx.x, lane = tid & 63, wid = tid >> 6;
    const int i0 = blockIdx.x * 16;
    const int h = blockIdx.y, b = blockIdx.z;
    const size_t bh = (size_t)(b * H_ + h);
    const int g = lane >> 4;                  // quad group 0..3
    const int cl = lane & 15;                 // col-lane

    if (flag[0] != 0) {
        for (int i2 = tid; i2 < N_; i2 += 256) smask[i2] = mraw[b * N_ + i2];
    } else {
        const int* mi = (const int*)mraw;
        for (int i2 = tid; i2 < N_; i2 += 256) smask[i2] = (unsigned char)(mi[b * N_ + i2] != 0);
    }

    // q fragments: rows i0+cl, K'=192 (6 k-steps of 32)
    s16x8 aq[6];
    const unsigned short* qrow = qp + (bh * N_ + i0 + cl) * 192 + g * 8;
    #pragma unroll
    for (int ks = 0; ks < 6; ++ks) aq[ks] = *(const s16x8*)(qrow + ks * 32);
    __syncthreads();

    // ---- dots + bias + mask, all results held in registers ----
    const float scale = 0.125f;               // HD^-0.5
    f32x4 acc[16];
    #pragma unroll
    for (int j = 0; j < 16; ++j) {
        const int nt = wid * 16 + j;
        const int col = nt * 16 + cl;
        float bv[4];
        #pragma unroll
        for (int r = 0; r < 4; ++r)
            bv[r] = attnbuf[(bh * N_ + i0 + g * 4 + r) * N_ + col];
        const unsigned short* krow = kp + (bh * N_ + nt * 16 + cl) * 192 + g * 8;
        f32x4 a = {0.f, 0.f, 0.f, 0.f};
        #pragma unroll
        for (int ks = 0; ks < 6; ++ks) {
            s16x8 bfrag = *(const s16x8*)(krow + ks * 32);
            a = __builtin_amdgcn_mfma_f32_16x16x32_bf16(aq[ks], bfrag, a, 0, 0, 0);
        }
        const bool mj = (smask[col] != 0);
        #pragma unroll
        for (int r = 0; r < 4; ++r)
            a[r] = mj ? -1e30f : fmaf(a[r], scale, bv[r]);
        acc[j] = a;
    }

    // ---- row max: regs -> 16-lane shuffle -> cross-wave LDS ----
    float m[4];
    #pragma unroll
    for (int r = 0; r < 4; ++r) {
        float mm = acc[0][r];
        #pragma unroll
        for (int j = 1; j < 16; ++j) mm = fmaxf(mm, acc[j][r]);
        m[r] = mm;
    }
    #pragma unroll
    for (int msk = 1; msk < 16; msk <<= 1)
        #pragma unroll
        for (int r = 0; r < 4; ++r) m[r] = fmaxf(m[r], __shfl_xor(m[r], msk));
    if (cl == 0)
        #pragma unroll
        for (int r = 0; r < 4; ++r) redm[g * 4 + r][wid] = m[r];
    __syncthreads();
    #pragma unroll
    for (int r = 0; r < 4; ++r) {
        int row = g * 4 + r;
        m[r] = fmaxf(fmaxf(redm[row][0], redm[row][1]), fmaxf(redm[row][2], redm[row][3]));
    }

    // ---- exp (in place) + row sum ----
    float s[4] = {0.f, 0.f, 0.f, 0.f};
    #pragma unroll
    for (int j = 0; j < 16; ++j)
        #pragma unroll
        for (int r = 0; r < 4; ++r) {
            float e = __expf(acc[j][r] - m[r]);
            acc[j][r] = e;
            s[r] += e;
        }
    #pragma unroll
    for (int msk = 1; msk < 16; msk <<= 1)
        #pragma unroll
        for (int r = 0; r < 4; ++r) s[r] += __shfl_xor(s[r], msk);
    if (cl == 0)
        #pragma unroll
        for (int r = 0; r < 4; ++r) reds[g * 4 + r][wid] = s[r];
    __syncthreads();
    float sinv[4];
    #pragma unroll
    for (int r = 0; r < 4; ++r) {
        int row = g * 4 + r;
        sinv[r] = 1.0f / (reds[row][0] + reds[row][1] + reds[row][2] + reds[row][3]);
    }

    // ---- attn write (from regs, 4x64B segments/inst) + P_lds bf16 write ----
    float* gattn = attnbuf + (bh * N_ + i0) * N_;
    char* Pb = (char*)P;
    #pragma unroll
    for (int j = 0; j < 16; ++j) {
        const int nt = wid * 16 + j;
        const int col = nt * 16 + cl;
        #pragma unroll
        for (int r = 0; r < 4; ++r) {
            const int row = g * 4 + r;
            float e = acc[j][r];
            gattn[(size_t)row * N_ + col] = e * sinv[r];
            int byte = row * 2048 + ((col * 2) ^ ((row & 7) << 4));
            *(unsigned short*)(Pb + byte) = f2bf(e);
        }
    }
    __syncthreads();

    // ---- PV: wave w covers d-tile w*16; K = 1024; A from swizzled P (b128) ----
    {
        const int d0 = wid * 16;
        f32x4 acc2 = {0.f, 0.f, 0.f, 0.f};
        const unsigned short* vrow = vT + (bh * HD_ + d0 + cl) * N_ + g * 8;
        const int rowA = cl;
        const int swz = (rowA & 7) << 4;
        for (int kk = 0; kk < N_; kk += 32) {
            s16x8 bfrag = *(const s16x8*)(vrow + kk);
            int byte = rowA * 2048 + (((kk + g * 8) * 2) ^ swz);
            s16x8 af = *(const s16x8*)(Pb + byte);
            acc2 = __builtin_amdgcn_mfma_f32_16x16x32_bf16(af, bfrag, acc2, 0, 0, 0);
        }
        #pragma unroll
        for (int r = 0; r < 4; ++r) {
            const int row = g * 4 + r;
            const int dd = d0 + cl;
            float v = acc2[r] * sinv[r];
            unsigned short hv = f2bf(v);
            size_t o = ((size_t)(b * N_) + i0 + row) * D_ + h * HD_ + dd;
            avh[o] = hv;
            avl[o] = f2bf(v - bf2f(hv));
        }
    }
}

extern "C" void kernel_launch(void* const* d_in, const int* in_sizes, int n_in,
                              void* d_out, int out_size, void* d_ws, size_t ws_size,
                              hipStream_t stream) {
    (void)in_sizes; (void)n_in; (void)out_size; (void)ws_size;
    const float* x      = (const float*)d_in[0];
    const float* coords = (const float*)d_in[1];
    const unsigned char* kpm = (const unsigned char*)d_in[2];
    const float* alpha  = (const float*)d_in[3];
    const float* W1     = (const float*)d_in[4];
    const float* b1     = (const float*)d_in[5];
    const float* W2     = (const float*)d_in[6];
    const float* b2     = (const float*)d_in[7];
    const float* Wqkv   = (const float*)d_in[8];
    const float* Wout   = (const float*)d_in[9];
    const float* bout   = (const float*)d_in[10];

    float* out  = (float*)d_out;                     // [B,N,D] = [4096,512]
    float* attn = out + (size_t)B_ * N_ * D_;        // [B,H,N,N] (also bias staging)

    // ---- workspace carve ----
    char* w = (char*)d_ws;
    auto alloc = [&](size_t bytes) { char* p = w; w += (bytes + 255) & ~(size_t)255; return p; };
    const size_t SZ_X  = (size_t)B_ * N_ * D_;       // 2,097,152
    const size_t SZ_WQ = (size_t)3 * D_ * D_;        // 786,432
    const size_t SZ_WO = (size_t)D_ * D_;            // 262,144
    unsigned short* x_hi = (unsigned short*)alloc(SZ_X * 2);
    unsigned short* x_lo = (unsigned short*)alloc(SZ_X * 2);
    unsigned short* wq_hi = (unsigned short*)alloc(SZ_WQ * 2);
    unsigned short* wq_lo = (unsigned short*)alloc(SZ_WQ * 2);
    unsigned short* wo_hi = (unsigned short*)alloc(SZ_WO * 2);
    unsigned short* wo_lo = (unsigned short*)alloc(SZ_WO * 2);
    float* qkv = (float*)alloc((size_t)B_ * N_ * 3 * D_ * 4);           // 25.2 MB
    unsigned short* qp = (unsigned short*)alloc((size_t)B_ * H_ * N_ * 192 * 2);
    unsigned short* kp = (unsigned short*)alloc((size_t)B_ * H_ * N_ * 192 * 2);
    unsigned short* vT = (unsigned short*)alloc((size_t)B_ * H_ * HD_ * N_ * 2);
    unsigned short* av_hi = (unsigned short*)alloc(SZ_X * 2);
    unsigned short* av_lo = (unsigned short*)alloc(SZ_X * 2);
    int* flag = (int*)alloc(256);

    // 1. splits
    k_split<<<(int)((SZ_X + 255) / 256), 256, 0, stream>>>(x, x_hi, x_lo, (int)SZ_X);
    k_split<<<(int)((SZ_WQ + 255) / 256), 256, 0, stream>>>(Wqkv, wq_hi, wq_lo, (int)SZ_WQ);
    k_split<<<(int)((SZ_WO + 255) / 256), 256, 0, stream>>>(Wout, wo_hi, wo_lo, (int)SZ_WO);
    // 2. mask layout detect
    k_mask_detect<<<1, 256, 0, stream>>>(kpm, flag);
    // 3. qkv projection: [4096,1536] = x[4096,512] @ Wqkv[1536,512]^T
    k_gemm3<<<dim3(64, 12), 256, 0, stream>>>(x_hi, x_lo, wq_hi, wq_lo, qkv, nullptr,
                                              B_ * N_, 3 * D_, D_);
    // 4. rearrange q', k', vT
    k_rearrange<<<(B_ * H_ * N_ * HD_) / 256, 256, 0, stream>>>(qkv, qp, kp);
    k_vtrans<<<dim3(16, H_, B_), 256, 0, stream>>>(qkv, vT);
    // 5. pairwise MLP bias -> attn region of d_out
    k_bias<<<(B_ * N_ * N_) / 256, 256, 0, stream>>>(coords, alpha, W1, b1, W2, b2, attn);
    // 6. fused attention (reads bias from attn region, overwrites with attn)
    k_attn<<<dim3(64, H_, B_), 256, 0, stream>>>(qp, kp, vT, attn, kpm, flag, av_hi, av_lo);
    // 7. output projection: out[4096,512] = av[4096,512] @ Wout[512,512]^T + bout
    k_gemm3<<<dim3(64, 4), 256, 0, stream>>>(av_hi, av_lo, wo_hi, wo_lo, out, bout,
                                             B_ * N_, D_, D_);
}

// Round 10
// 341.559 us; speedup vs baseline: 1.4433x; 1.0179x over previous
//
#include <hip/hip_runtime.h>
#include <hip/hip_fp16.h>
#include <stdint.h>
#include <math.h>

#define B_  4
#define N_  1024
#define D_  512
#define H_  8
#define HD_ 64

typedef short s16x8 __attribute__((ext_vector_type(8)));
typedef float f32x4 __attribute__((ext_vector_type(4)));

__device__ __forceinline__ unsigned short f2bf(float f) {
    unsigned u = __float_as_uint(f);
    u += 0x7fffu + ((u >> 16) & 1u);      // RNE
    return (unsigned short)(u >> 16);
}
__device__ __forceinline__ float bf2f(unsigned short h) {
    return __uint_as_float(((unsigned)h) << 16);
}

// fast exact-erf gelu: A&S 7.1.26 rational, |erf err| <= 1.5e-7, branch-free
__device__ __forceinline__ float fast_gelu(float x) {
    float ax = fabsf(x) * 0.7071067811865476f;          // |x|/sqrt(2)
    float t  = __builtin_amdgcn_rcpf(fmaf(0.3275911f, ax, 1.0f));
    float e  = __expf(-ax * ax);
    float poly = t * fmaf(t, fmaf(t, fmaf(t, fmaf(t, 1.061405429f, -1.453152027f),
                                          1.421413741f), -0.284496736f), 0.254829592f);
    float erfv = 1.0f - poly * e;                        // erf(|x|/sqrt2)
    float s = copysignf(erfv, x);
    return 0.5f * x * (1.0f + s);
}

// ---------------- split f32 -> (hi, lo) bf16 ----------------
__global__ void k_split(const float* __restrict__ s, unsigned short* __restrict__ h,
                        unsigned short* __restrict__ l, int n) {
    int i = blockIdx.x * 256 + threadIdx.x;
    if (i < n) {
        float x = s[i];
        unsigned short hb = f2bf(x);
        h[i] = hb;
        l[i] = f2bf(x - bf2f(hb));
    }
}

// ---------------- mask layout detection ----------------
__global__ void k_mask_detect(const unsigned char* __restrict__ m, int* __restrict__ flag) {
    __shared__ int s;
    if (threadIdx.x == 0) s = 0;
    __syncthreads();
    int found = 0;
    for (int i = threadIdx.x; i < B_ * N_; i += 256)
        if ((i & 3) && m[i]) found = 1;
    if (found) atomicOr(&s, 1);
    __syncthreads();
    if (threadIdx.x == 0) flag[0] = s;
}

// ---------------- split-bf16 GEMM: C[M,N] = A[M,K] @ B[N,K]^T (+bias) ----------------
__global__ __launch_bounds__(256) void k_gemm3(
    const unsigned short* __restrict__ Ah, const unsigned short* __restrict__ Al,
    const unsigned short* __restrict__ Bwh, const unsigned short* __restrict__ Bwl,
    float* __restrict__ C, const float* __restrict__ bias, int M, int Nn, int K)
{
    constexpr int BM = 64, BN = 128, BK = 64;
    __shared__ unsigned short At[BM * BK];
    __shared__ unsigned short Bt[BN * BK];
    const int tid = threadIdx.x, lane = tid & 63, wid = tid >> 6;
    const int m0 = blockIdx.x * BM, n0 = blockIdx.y * BN;
    const int wm = wid >> 1, wn = wid & 1;   // wave tile: 32 rows x 64 cols
    f32x4 acc[2][4] = {};
    const unsigned short* Aps[3] = {Ah, Ah, Al};
    const unsigned short* Bps[3] = {Bwh, Bwl, Bwh};

    for (int combo = 0; combo < 3; ++combo) {
        const unsigned short* __restrict__ Ap = Aps[combo];
        const unsigned short* __restrict__ Bp = Bps[combo];
        for (int k0 = 0; k0 < K; k0 += BK) {
            s16x8 sa[2], sb[4];
            #pragma unroll
            for (int r = 0; r < 2; ++r) {
                int s = r * 256 + tid, row = s >> 3, c8 = s & 7;
                sa[r] = *(const s16x8*)(Ap + (size_t)(m0 + row) * K + k0 + c8 * 8);
            }
            #pragma unroll
            for (int r = 0; r < 4; ++r) {
                int s = r * 256 + tid, row = s >> 3, c8 = s & 7;
                sb[r] = *(const s16x8*)(Bp + (size_t)(n0 + row) * K + k0 + c8 * 8);
            }
            __syncthreads();  // previous-iter LDS reads done
            #pragma unroll
            for (int r = 0; r < 2; ++r) { int s = r * 256 + tid; *(s16x8*)(At + s * 8) = sa[r]; }
            #pragma unroll
            for (int r = 0; r < 4; ++r) { int s = r * 256 + tid; *(s16x8*)(Bt + s * 8) = sb[r]; }
            __syncthreads();
            #pragma unroll
            for (int kk = 0; kk < BK; kk += 32) {
                s16x8 a[2], bb[4];
                #pragma unroll
                for (int fm = 0; fm < 2; ++fm)
                    a[fm] = *(const s16x8*)(At + (wm * 32 + fm * 16 + (lane & 15)) * BK + kk + (lane >> 4) * 8);
                #pragma unroll
                for (int fn = 0; fn < 4; ++fn)
                    bb[fn] = *(const s16x8*)(Bt + (wn * 64 + fn * 16 + (lane & 15)) * BK + kk + (lane >> 4) * 8);
                #pragma unroll
                for (int fm = 0; fm < 2; ++fm)
                    #pragma unroll
                    for (int fn = 0; fn < 4; ++fn)
                        acc[fm][fn] = __builtin_amdgcn_mfma_f32_16x16x32_bf16(a[fm], bb[fn], acc[fm][fn], 0, 0, 0);
            }
        }
    }
    #pragma unroll
    for (int fm = 0; fm < 2; ++fm)
        #pragma unroll
        for (int fn = 0; fn < 4; ++fn)
            #pragma unroll
            for (int r = 0; r < 4; ++r) {
                int row  = m0 + wm * 32 + fm * 16 + (lane >> 4) * 4 + r;
                int coln = n0 + wn * 64 + fn * 16 + (lane & 15);
                float v = acc[fm][fn][r];
                if (bias) v += bias[coln];
                C[(size_t)row * Nn + coln] = v;
            }
}

// ---------------- rearrange qkv -> q' (=[hi|hi|lo]) / k' (=[hi|lo|hi]) bf16 [B,H,N,192] ----------------
__global__ void k_rearrange(const float* __restrict__ qkv, unsigned short* __restrict__ qp,
                            unsigned short* __restrict__ kp) {
    int t = blockIdx.x * 256 + threadIdx.x;
    int d = t & 63, n = (t >> 6) & 1023, h = (t >> 16) & 7, b = t >> 19;
    const float* src = qkv + ((size_t)(b * N_ + n)) * (3 * D_) + h * HD_ + d;
    float q = src[0], k = src[D_];
    unsigned short qh = f2bf(q), ql = f2bf(q - bf2f(qh));
    unsigned short kh = f2bf(k), kl = f2bf(k - bf2f(kh));
    size_t base = ((size_t)(b * H_ + h) * N_ + n) * 192;
    qp[base + d] = qh; qp[base + 64 + d] = qh; qp[base + 128 + d] = ql;
    kp[base + d] = kh; kp[base + 64 + d] = kl; kp[base + 128 + d] = kh;
}

// ---------------- v -> vT bf16 [B,H,HD,N] (LDS transpose) ----------------
__global__ void k_vtrans(const float* __restrict__ qkv, unsigned short* __restrict__ vT) {
    __shared__ unsigned short T[64][65];
    int n0 = blockIdx.x * 64, h = blockIdx.y, b = blockIdx.z;
    int tid = threadIdx.x;
    #pragma unroll
    for (int rep = 0; rep < 16; ++rep) {
        int idx = rep * 256 + tid;
        int nl = idx >> 6, d = idx & 63;
        T[nl][d] = f2bf(qkv[((size_t)(b * N_ + n0 + nl)) * (3 * D_) + 2 * D_ + h * HD_ + d]);
    }
    __syncthreads();
    #pragma unroll
    for (int rep = 0; rep < 16; ++rep) {
        int idx = rep * 256 + tid;
        int dl = idx >> 6, nl = idx & 63;
        vT[((size_t)(b * H_ + h) * HD_ + dl) * N_ + n0 + nl] = T[nl][dl];
    }
}

// ---------------- pairwise MLP bias -> f16 [B,H,N,N] (alpha & valid-mask folded) ----------------
// Grouped structure (4 groups x 8 ch, runtime loop) bounds registers structurally.
__global__ __launch_bounds__(256) void k_bias(
    const float* __restrict__ coords, const float* __restrict__ alpha,
    const float* __restrict__ W1, const float* __restrict__ b1,
    const float* __restrict__ W2, const float* __restrict__ b2,
    unsigned short* __restrict__ biasH)
{
    __shared__ float sW1[128], sb1[32], sW2[256], sb2[8];
    int tid = threadIdx.x;
    if (tid < 128) sW1[tid] = W1[tid];
    if (tid < 32)  sb1[tid] = b1[tid];
    sW2[tid] = W2[tid];
    if (tid < 8)   sb2[tid] = b2[tid];
    __syncthreads();

    size_t t = (size_t)blockIdx.x * 256 + tid;
    int j = (int)(t & 1023), i = (int)((t >> 10) & 1023), b = (int)(t >> 20);
    const float* ci = coords + ((size_t)b * N_ + i) * 3;
    const float* cj = coords + ((size_t)b * N_ + j) * 3;
    float dx = ci[0] - cj[0], dy = ci[1] - cj[1], dz = ci[2] - cj[2];
    float dist = sqrtf(dx * dx + dy * dy + dz * dz);

    float acc[8];
    #pragma unroll
    for (int hh = 0; hh < 8; ++hh) acc[hh] = sb2[hh];

    #pragma unroll 1
    for (int g = 0; g < 4; ++g) {            // 4 groups x 8 channels; runtime loop
        float gg[8];
        #pragma unroll
        for (int cc = 0; cc < 8; ++cc) {
            int c = g * 8 + cc;
            float p = fmaf(sW1[c * 4], dx,
                      fmaf(sW1[c * 4 + 1], dy,
                      fmaf(sW1[c * 4 + 2], dz,
                      fmaf(sW1[c * 4 + 3], dist, sb1[c]))));
            gg[cc] = fast_gelu(p);
        }
        #pragma unroll
        for (int hh = 0; hh < 8; ++hh)
            #pragma unroll
            for (int cc = 0; cc < 8; ++cc)
                acc[hh] = fmaf(sW2[hh * 32 + g * 8 + cc], gg[cc], acc[hh]);
    }

    float vfac = (i >= 1 && j >= 1) ? alpha[0] : 0.f;   // NS=1 special-token zeroing + alpha fold
    #pragma unroll
    for (int hh = 0; hh < 8; ++hh) {
        __half hv = __float2half(vfac * acc[hh]);
        biasH[(((size_t)(b * H_ + hh)) * N_ + i) * N_ + j] = *(unsigned short*)&hv;
    }
}

// ---------------- fused attention, register-resident logits ----------------
// 16 rows/block, 4 waves. Logits in acc[16] f32x4 (AGPR). Bias read as f16.
// launch_bounds(256,4): empirically caps VGPR at 64 -> 64V+64A = 128 unified
// = 4 waves/SIMD -> 4 blocks/CU (LDS 34KB). Only big LDS: swizzled bf16 P.
__global__ __launch_bounds__(256, 4) void k_attn(
    const unsigned short* __restrict__ qp, const unsigned short* __restrict__ kp,
    const unsigned short* __restrict__ vT,
    const unsigned short* __restrict__ biasH,   // f16 [B,H,N,N]
    float* __restrict__ attnout,                // f32 [B,H,N,N] (pure output)
    const unsigned char* __restrict__ mraw, const int* __restrict__ flag,
    unsigned short* __restrict__ avh, unsigned short* __restrict__ avl)  // [B,N,D] hi/lo
{
    __shared__ unsigned short P[16 * 1024];   // 32 KB, swizzled: byte ^= (row&7)<<4
    __shared__ unsigned char smask[N_];
    __shared__ float redm[16][4];
    __shared__ float reds[16][4];
    const int tid = threadIdx.x, lane = tid & 63, wid = tid >> 6;
    const int i0 = blockIdx.x * 16;
    const int h = blockIdx.y, b = blockIdx.z;
    const size_t bh = (size_t)(b * H_ + h);
    const int g = lane >> 4;                  // quad group 0..3
    const int cl = lane & 15;                 // col-lane

    if (flag[0] != 0) {
        for (int i2 = tid; i2 < N_; i2 += 256) smask[i2] = mraw[b * N_ + i2];
    } else {
        const int* mi = (const int*)mraw;
        for (int i2 = tid; i2 < N_; i2 += 256) smask[i2] = (unsigned char)(mi[b * N_ + i2] != 0);
    }

    // q fragments: rows i0+cl, K'=192 (6 k-steps of 32)
    s16x8 aq[6];
    const unsigned short* qrow = qp + (bh * N_ + i0 + cl) * 192 + g * 8;
    #pragma unroll
    for (int ks = 0; ks < 6; ++ks) aq[ks] = *(const s16x8*)(qrow + ks * 32);
    __syncthreads();

    // ---- dots + bias + mask, all results held in registers ----
    const float scale = 0.125f;               // HD^-0.5
    f32x4 acc[16];
    #pragma unroll
    for (int j = 0; j < 16; ++j) {
        const int nt = wid * 16 + j;
        const int col = nt * 16 + cl;
        const unsigned short* bcol = biasH + (bh * N_ + i0 + g * 4) * N_ + col;
        unsigned short bh0 = bcol[0];
        unsigned short bh1 = bcol[N_];
        unsigned short bh2 = bcol[2 * N_];
        unsigned short bh3 = bcol[3 * N_];
        const unsigned short* krow = kp + (bh * N_ + nt * 16 + cl) * 192 + g * 8;
        f32x4 a = {0.f, 0.f, 0.f, 0.f};
        #pragma unroll
        for (int ks = 0; ks < 6; ++ks) {
            s16x8 bfrag = *(const s16x8*)(krow + ks * 32);
            a = __builtin_amdgcn_mfma_f32_16x16x32_bf16(aq[ks], bfrag, a, 0, 0, 0);
        }
        const bool mj = (smask[col] != 0);
        float bv0 = __half2float(*(const __half*)&bh0);
        float bv1 = __half2float(*(const __half*)&bh1);
        float bv2 = __half2float(*(const __half*)&bh2);
        float bv3 = __half2float(*(const __half*)&bh3);
        a[0] = mj ? -1e30f : fmaf(a[0], scale, bv0);
        a[1] = mj ? -1e30f : fmaf(a[1], scale, bv1);
        a[2] = mj ? -1e30f : fmaf(a[2], scale, bv2);
        a[3] = mj ? -1e30f : fmaf(a[3], scale, bv3);
        acc[j] = a;
    }

    // ---- row max: regs -> 16-lane shuffle -> cross-wave LDS ----
    float m[4];
    #pragma unroll
    for (int r = 0; r < 4; ++r) {
        float mm = acc[0][r];
        #pragma unroll
        for (int j = 1; j < 16; ++j) mm = fmaxf(mm, acc[j][r]);
        m[r] = mm;
    }
    #pragma unroll
    for (int msk = 1; msk < 16; msk <<= 1)
        #pragma unroll
        for (int r = 0; r < 4; ++r) m[r] = fmaxf(m[r], __shfl_xor(m[r], msk));
    if (cl == 0)
        #pragma unroll
        for (int r = 0; r < 4; ++r) redm[g * 4 + r][wid] = m[r];
    __syncthreads();
    #pragma unroll
    for (int r = 0; r < 4; ++r) {
        int row = g * 4 + r;
        m[r] = fmaxf(fmaxf(redm[row][0], redm[row][1]), fmaxf(redm[row][2], redm[row][3]));
    }

    // ---- exp (in place) + row sum ----
    float s[4] = {0.f, 0.f, 0.f, 0.f};
    #pragma unroll
    for (int j = 0; j < 16; ++j)
        #pragma unroll
        for (int r = 0; r < 4; ++r) {
            float e = __expf(acc[j][r] - m[r]);
            acc[j][r] = e;
            s[r] += e;
        }
    #pragma unroll
    for (int msk = 1; msk < 16; msk <<= 1)
        #pragma unroll
        for (int r = 0; r < 4; ++r) s[r] += __shfl_xor(s[r], msk);
    if (cl == 0)
        #pragma unroll
        for (int r = 0; r < 4; ++r) reds[g * 4 + r][wid] = s[r];
    __syncthreads();
    float sinv[4];
    #pragma unroll
    for (int r = 0; r < 4; ++r) {
        int row = g * 4 + r;
        sinv[r] = 1.0f / (reds[row][0] + reds[row][1] + reds[row][2] + reds[row][3]);
    }

    // ---- attn write (from regs) + P_lds bf16 write ----
    float* gattn = attnout + (bh * N_ + i0) * N_;
    char* Pb = (char*)P;
    #pragma unroll
    for (int j = 0; j < 16; ++j) {
        const int nt = wid * 16 + j;
        const int col = nt * 16 + cl;
        #pragma unroll
        for (int r = 0; r < 4; ++r) {
            const int row = g * 4 + r;
            float e = acc[j][r];
            gattn[(size_t)row * N_ + col] = e * sinv[r];
            int byte = row * 2048 + ((col * 2) ^ ((row & 7) << 4));
            *(unsigned short*)(Pb + byte) = f2bf(e);
        }
    }
    __syncthreads();

    // ---- PV: wave w covers d-tile w*16; K = 1024; A from swizzled P (b128) ----
    {
        const int d0 = wid * 16;
        f32x4 acc2 = {0.f, 0.f, 0.f, 0.f};
        const unsigned short* vrow = vT + (bh * HD_ + d0 + cl) * N_ + g * 8;
        const int rowA = cl;
        const int swz = (rowA & 7) << 4;
        for (int kk = 0; kk < N_; kk += 32) {
            s16x8 bfrag = *(const s16x8*)(vrow + kk);
            int byte = rowA * 2048 + (((kk + g * 8) * 2) ^ swz);
            s16x8 af = *(const s16x8*)(Pb + byte);
            acc2 = __builtin_amdgcn_mfma_f32_16x16x32_bf16(af, bfrag, acc2, 0, 0, 0);
        }
        #pragma unroll
        for (int r = 0; r < 4; ++r) {
            const int row = g * 4 + r;
            const int dd = d0 + cl;
            float v = acc2[r] * sinv[r];
            unsigned short hv = f2bf(v);
            size_t o = ((size_t)(b * N_) + i0 + row) * D_ + h * HD_ + dd;
            avh[o] = hv;
            avl[o] = f2bf(v - bf2f(hv));
        }
    }
}

extern "C" void kernel_launch(void* const* d_in, const int* in_sizes, int n_in,
                              void* d_out, int out_size, void* d_ws, size_t ws_size,
                              hipStream_t stream) {
    (void)in_sizes; (void)n_in; (void)out_size; (void)ws_size;
    const float* x      = (const float*)d_in[0];
    const float* coords = (const float*)d_in[1];
    const unsigned char* kpm = (const unsigned char*)d_in[2];
    const float* alpha  = (const float*)d_in[3];
    const float* W1     = (const float*)d_in[4];
    const float* b1     = (const float*)d_in[5];
    const float* W2     = (const float*)d_in[6];
    const float* b2     = (const float*)d_in[7];
    const float* Wqkv   = (const float*)d_in[8];
    const float* Wout   = (const float*)d_in[9];
    const float* bout   = (const float*)d_in[10];

    float* out  = (float*)d_out;                     // [B,N,D] = [4096,512]
    float* attn = out + (size_t)B_ * N_ * D_;        // [B,H,N,N] (pure output now)

    // ---- workspace carve: long-lived first, then stage-union region ----
    char* w = (char*)d_ws;
    auto alloc = [&](size_t bytes) { char* p = w; w += (bytes + 255) & ~(size_t)255; return p; };
    const size_t SZ_X  = (size_t)B_ * N_ * D_;       // 2,097,152
    const size_t SZ_WQ = (size_t)3 * D_ * D_;        // 786,432
    const size_t SZ_WO = (size_t)D_ * D_;            // 262,144
    const size_t SZ_BH = (size_t)B_ * H_ * N_ * N_;  // 33,554,432 (f16 bias elems)

    // long-lived
    unsigned short* wo_hi = (unsigned short*)alloc(SZ_WO * 2);
    unsigned short* wo_lo = (unsigned short*)alloc(SZ_WO * 2);
    unsigned short* qp = (unsigned short*)alloc((size_t)B_ * H_ * N_ * 192 * 2);
    unsigned short* kp = (unsigned short*)alloc((size_t)B_ * H_ * N_ * 192 * 2);
    unsigned short* vT = (unsigned short*)alloc((size_t)B_ * H_ * HD_ * N_ * 2);
    unsigned short* av_hi = (unsigned short*)alloc(SZ_X * 2);
    unsigned short* av_lo = (unsigned short*)alloc(SZ_X * 2);
    int* flag = (int*)alloc(256);

    // union region: stage-1 (x/wq staging + qkv) vs stage-2 (f16 bias)
    char* uni = (char*)alloc(0);
    unsigned short* x_hi = (unsigned short*)uni;                      // 4 MB
    unsigned short* x_lo = x_hi + SZ_X;                               // 4 MB
    unsigned short* wq_hi = x_lo + SZ_X;                              // 1.5 MB
    unsigned short* wq_lo = wq_hi + SZ_WQ;                            // 1.5 MB
    float* qkv = (float*)(wq_lo + SZ_WQ);                             // 25.2 MB
    unsigned short* biasH = (unsigned short*)uni;                     // 67 MB (stage-2, aliases all above)

    // 1. splits
    k_split<<<(int)((SZ_X + 255) / 256), 256, 0, stream>>>(x, x_hi, x_lo, (int)SZ_X);
    k_split<<<(int)((SZ_WQ + 255) / 256), 256, 0, stream>>>(Wqkv, wq_hi, wq_lo, (int)SZ_WQ);
    k_split<<<(int)((SZ_WO + 255) / 256), 256, 0, stream>>>(Wout, wo_hi, wo_lo, (int)SZ_WO);
    // 2. mask layout detect
    k_mask_detect<<<1, 256, 0, stream>>>(kpm, flag);
    // 3. qkv projection: [4096,1536] = x[4096,512] @ Wqkv[1536,512]^T
    k_gemm3<<<dim3(64, 12), 256, 0, stream>>>(x_hi, x_lo, wq_hi, wq_lo, qkv, nullptr,
                                              B_ * N_, 3 * D_, D_);
    // 4. rearrange q', k', vT  (last consumers of stage-1 buffers)
    k_rearrange<<<(B_ * H_ * N_ * HD_) / 256, 256, 0, stream>>>(qkv, qp, kp);
    k_vtrans<<<dim3(16, H_, B_), 256, 0, stream>>>(qkv, vT);
    // 5. pairwise MLP bias -> f16 biasH (stage-2 reuse of union region)
    k_bias<<<(B_ * N_ * N_) / 256, 256, 0, stream>>>(coords, alpha, W1, b1, W2, b2, biasH);
    // 6. fused attention
    k_attn<<<dim3(64, H_, B_), 256, 0, stream>>>(qp, kp, vT, biasH, attn, kpm, flag, av_hi, av_lo);
    // 7. output projection: out[4096,512] = av[4096,512] @ Wout[512,512]^T + bout
    k_gemm3<<<dim3(64, 4), 256, 0, stream>>>(av_hi, av_lo, wo_hi, wo_lo, out, bout,
                                             B_ * N_, D_, D_);
    (void)SZ_BH;
}